// Round 1
// baseline (100.820 us; speedup 1.0000x reference)
//
#include <hip/hip_runtime.h>

// EdgeNetwork: out[e] = sigmoid( tanh( [x[col[e]], x[row[e]]] @ W1 + b1 ) @ W2 + b2 )
// E = 3.2M edges, IN=16, HID=64.
//
// Strategy: bf16 MFMA (16x16x32) computes the [16-edge x 64-hid] first layer
// per wave with zero LDS: A-fragment layout (lane l: A[l%16][8*(l>>4)+b])
// matches "each lane gathers 8 contiguous features of one node". W1/b1/W2
// live in registers (preloaded once per wave). Layer 2 is a per-lane partial
// dot + 4-level shfl_xor reduce across the 16-lane column group.
//
// x is pre-converted to bf16 in d_ws (halves gather bytes, kills per-edge cvt).
// edge_index dtype (int32 vs int64) is detected on-device (odd 32-bit words
// all zero over 64 samples => int64).

typedef __attribute__((ext_vector_type(8))) short bf16x8;
typedef __attribute__((ext_vector_type(4))) float f32x4;
typedef __attribute__((ext_vector_type(4))) unsigned short u16x4;

#define LOG2E 1.4426950408889634f

#if defined(__has_builtin)
#if __has_builtin(__builtin_amdgcn_exp2f)
#define EXP2F __builtin_amdgcn_exp2f
#endif
#if __has_builtin(__builtin_amdgcn_rcpf)
#define RCPF __builtin_amdgcn_rcpf
#endif
#endif
#ifndef EXP2F
#define EXP2F exp2f
#endif
#ifndef RCPF
#define RCPF(x) (1.0f / (x))
#endif

__device__ __forceinline__ unsigned short f2bf(float f) {
    // round-to-nearest-even fp32 -> bf16 (no NaN in this problem's data)
    unsigned u = __float_as_uint(f);
    u += 0x7fffu + ((u >> 16) & 1u);
    return (unsigned short)(u >> 16);
}

__device__ __forceinline__ float fast_tanh(float x) {
    // tanh(x) = 1 - 2/(1 + e^{2x}); e^{2x} = 2^(x * 2*log2 e)
    // saturates correctly: x->+inf => 1, x->-inf => -1
    float e = EXP2F(x * (2.0f * LOG2E));
    return 1.0f - 2.0f * RCPF(1.0f + e);
}

__device__ __forceinline__ float fast_sigmoid(float x) {
    float e = EXP2F(-x * LOG2E);
    return RCPF(1.0f + e);
}

// ---- edge_index dtype detector: int64 data has zero high words ----
__global__ void detect_idx64(const unsigned* __restrict__ ei, int* __restrict__ flag) {
    unsigned v = ei[2 * threadIdx.x + 1];          // odd 32-bit words
    unsigned long long nz = __ballot(v != 0u);
    if (threadIdx.x == 0) flag[0] = (nz == 0ull) ? 1 : 0;
}

// ---- x (fp32) -> xb (bf16) ----
__global__ void cvt_x_bf16(const float* __restrict__ x, unsigned short* __restrict__ xb, int n) {
    int i = (blockIdx.x * blockDim.x + threadIdx.x) * 4;
    if (i >= n) return;
    f32x4 v = *(const f32x4*)(x + i);
    u16x4 o;
    o[0] = f2bf(v[0]); o[1] = f2bf(v[1]); o[2] = f2bf(v[2]); o[3] = f2bf(v[3]);
    *(u16x4*)(xb + i) = o;
}

// ---- main fused kernel: one 16-edge tile per wave per iteration ----
template <bool USE_XB>
__global__ void __launch_bounds__(256)
edge_mlp(const void* __restrict__ ei,
         const float* __restrict__ x,
         const unsigned short* __restrict__ xb,
         const float* __restrict__ W1,
         const float* __restrict__ b1,
         const float* __restrict__ W2,
         const float* __restrict__ b2,
         float* __restrict__ out,
         const int* __restrict__ flag,
         int E, int ntiles)
{
    const int lane = threadIdx.x & 63;
    const int l15  = lane & 15;        // A row (edge within tile) / B,N column
    const int lg   = lane >> 4;        // k-group 0..3 (k = 8*lg .. 8*lg+7)
    const int gwave  = blockIdx.x * (blockDim.x >> 6) + (threadIdx.x >> 6);
    const int nwaves = gridDim.x * (blockDim.x >> 6);

    const int idx64 = flag ? flag[0] : 0;

    // Preload W1 B-fragments (w1f[jb][b] = W1[8*lg+b][16*jb+l15]), b1, W2.
    bf16x8 w1f[4];
    float  b1v[4], w2v[4];
#pragma unroll
    for (int jb = 0; jb < 4; ++jb) {
        union { bf16x8 v; unsigned short u[8]; } t;
#pragma unroll
        for (int b = 0; b < 8; ++b)
            t.u[b] = f2bf(W1[(8 * lg + b) * 64 + 16 * jb + l15]);
        w1f[jb] = t.v;
        b1v[jb] = b1[16 * jb + l15];
        w2v[jb] = W2[16 * jb + l15];
    }
    const float bias2 = b2[0];

    // k 0..15 = bi = x[col] = edge_index[1]; k 16..31 = bo = x[row] = edge_index[0]
    const int which = (lane < 32) ? 1 : 0;
    const int feat8 = (lg & 1) * 8;

    for (int tile = gwave; tile < ntiles; tile += nwaves) {
        int e  = tile * 16 + l15;
        int ec = e < E ? e : E - 1;
        int node;
        if (idx64) node = (int)((const long long*)ei)[(size_t)which * E + ec];
        else       node = ((const int*)ei)[(size_t)which * E + ec];

        bf16x8 af;
        if (USE_XB) {
            af = *(const bf16x8*)(xb + (size_t)node * 16 + feat8);
        } else {
            const float* px = x + (size_t)node * 16 + feat8;
            f32x4 v0 = *(const f32x4*)px;
            f32x4 v1 = *(const f32x4*)(px + 4);
            union { bf16x8 v; unsigned short u[8]; } t;
#pragma unroll
            for (int b = 0; b < 4; ++b) { t.u[b] = f2bf(v0[b]); t.u[b + 4] = f2bf(v1[b]); }
            af = t.v;
        }

        // Layer 1 (4 MFMAs over hid blocks) fused with tanh + layer-2 partials.
        float p0 = 0.f, p1 = 0.f, p2 = 0.f, p3 = 0.f;
#pragma unroll
        for (int jb = 0; jb < 4; ++jb) {
            f32x4 c = { b1v[jb], b1v[jb], b1v[jb], b1v[jb] };   // bias by column
            f32x4 acc = __builtin_amdgcn_mfma_f32_16x16x32_bf16(af, w1f[jb], c, 0, 0, 0);
            p0 += fast_tanh(acc[0]) * w2v[jb];
            p1 += fast_tanh(acc[1]) * w2v[jb];
            p2 += fast_tanh(acc[2]) * w2v[jb];
            p3 += fast_tanh(acc[3]) * w2v[jb];
        }
        float p[4] = { p0, p1, p2, p3 };
        // reduce across the 16 lanes of each column group (xor bits 0..3)
#pragma unroll
        for (int r = 0; r < 4; ++r) {
            p[r] += __shfl_xor(p[r], 1);
            p[r] += __shfl_xor(p[r], 2);
            p[r] += __shfl_xor(p[r], 4);
            p[r] += __shfl_xor(p[r], 8);
            p[r] = fast_sigmoid(p[r] + bias2);
        }
        // D row m = 4*lg + r  ->  out[tile*16 + m]; lane with l15==r stores reg r
        int mbase = tile * 16 + 4 * lg;
#pragma unroll
        for (int r = 0; r < 4; ++r) {
            if (l15 == r && (mbase + r) < E)
                out[mbase + r] = p[r];
        }
    }
}

extern "C" void kernel_launch(void* const* d_in, const int* in_sizes, int n_in,
                              void* d_out, int out_size, void* d_ws, size_t ws_size,
                              hipStream_t stream)
{
    const float* x  = (const float*)d_in[0];
    const void*  ei = d_in[1];
    const float* W1 = (const float*)d_in[2];
    const float* b1 = (const float*)d_in[3];
    const float* W2 = (const float*)d_in[4];
    const float* b2 = (const float*)d_in[5];
    float* out = (float*)d_out;

    const int E      = in_sizes[1] / 2;   // element count of edge_index / 2
    const int nx     = in_sizes[0];       // N_NODES * IN_DIM
    const int ntiles = (E + 15) / 16;

    int* flag = nullptr;
    unsigned short* xb = nullptr;
    bool use_xb = false;
    if (ws_size >= 4) flag = (int*)d_ws;
    if (ws_size >= 256 + (size_t)nx * 2) {
        xb = (unsigned short*)((char*)d_ws + 256);
        use_xb = true;
    }

    if (flag) detect_idx64<<<1, 64, 0, stream>>>((const unsigned*)ei, flag);
    if (use_xb) {
        int nth = (nx + 3) / 4;
        cvt_x_bf16<<<(nth + 255) / 256, 256, 0, stream>>>(x, xb, nx);
    }

    const int blocks = 2048;   // 8192 waves, ~24 tiles each; 2048 = full residency
    if (use_xb)
        edge_mlp<true ><<<blocks, 256, 0, stream>>>(ei, x, xb, W1, b1, W2, b2, out, flag, E, ntiles);
    else
        edge_mlp<false><<<blocks, 256, 0, stream>>>(ei, x, xb, W1, b1, W2, b2, out, flag, E, ntiles);
}

// Round 2
// 78.093 us; speedup vs baseline: 1.2910x; 1.2910x over previous
//
#include <hip/hip_runtime.h>

// EdgeNetwork: out[e] = sigmoid( tanh( [x[col[e]], x[row[e]]] @ W1 + b1 ) @ W2 + b2 )
// E = 3.2M edges, IN=16, HID=64.
//
// R2: swapped-operand MFMA. D = W1T_block @ Xconcat  => lane holds
// h[edge = lane&15][hid = 16*jb + 4*(lane>>4) + r]. Layer 2 collapses to a
// per-lane fma chain + 2 shfl_xor + 1 sigmoid + 1 coalesced 16-lane store.
// Algebra folded: W1,b1 pre-scaled by 2*log2(e) so tanh = 1 - 2*rcp(1+exp2(acc));
// w2*tanh = w2 - 2*w2*rcp(...) with per-lane sum(w2) as the accumulator base.
// Inner loop per hidden value: v_exp + v_add + v_rcp + v_fmac (2 VALU + 2 trans).

typedef __attribute__((ext_vector_type(8))) short bf16x8;
typedef __attribute__((ext_vector_type(4))) float f32x4;
typedef __attribute__((ext_vector_type(4))) unsigned short u16x4;

#define LOG2E 1.4426950408889634f

#if defined(__has_builtin)
#if __has_builtin(__builtin_amdgcn_exp2f)
#define EXP2F __builtin_amdgcn_exp2f
#endif
#if __has_builtin(__builtin_amdgcn_rcpf)
#define RCPF __builtin_amdgcn_rcpf
#endif
#endif
#ifndef EXP2F
#define EXP2F exp2f
#endif
#ifndef RCPF
#define RCPF(x) (1.0f / (x))
#endif

__device__ __forceinline__ unsigned short f2bf(float f) {
    unsigned u = __float_as_uint(f);
    u += 0x7fffu + ((u >> 16) & 1u);
    return (unsigned short)(u >> 16);
}

__device__ __forceinline__ float fast_sigmoid(float x) {
    float e = EXP2F(-x * LOG2E);
    return RCPF(1.0f + e);
}

// ---- edge_index dtype detector: int64 data has zero high 32-bit words ----
__global__ void detect_idx64(const unsigned* __restrict__ ei, int* __restrict__ flag) {
    unsigned v = ei[2 * threadIdx.x + 1];
    unsigned long long nz = __ballot(v != 0u);
    if (threadIdx.x == 0) flag[0] = (nz == 0ull) ? 1 : 0;
}

// ---- x (fp32) -> xb (bf16) ----
__global__ void cvt_x_bf16(const float* __restrict__ x, unsigned short* __restrict__ xb, int n) {
    int i = (blockIdx.x * blockDim.x + threadIdx.x) * 4;
    if (i >= n) return;
    f32x4 v = *(const f32x4*)(x + i);
    u16x4 o;
    o[0] = f2bf(v[0]); o[1] = f2bf(v[1]); o[2] = f2bf(v[2]); o[3] = f2bf(v[3]);
    *(u16x4*)(xb + i) = o;
}

// ---- main fused kernel: one 16-edge tile per wave per iteration ----
template <bool USE_XB>
__global__ void __launch_bounds__(256)
edge_mlp(const void* __restrict__ ei,
         const float* __restrict__ x,
         const unsigned short* __restrict__ xb,
         const float* __restrict__ W1,
         const float* __restrict__ b1,
         const float* __restrict__ W2,
         const float* __restrict__ b2,
         float* __restrict__ out,
         const int* __restrict__ flag,
         int E, int ntiles)
{
    const int lane = threadIdx.x & 63;
    const int l15  = lane & 15;        // edge within tile (B column)
    const int lg   = lane >> 4;        // k-group 0..3
    const int gwave  = blockIdx.x * (blockDim.x >> 6) + (threadIdx.x >> 6);
    const int nwaves = gridDim.x * (blockDim.x >> 6);

    const int idx64 = flag ? flag[0] : 0;
    const float S = 2.0f * LOG2E;

    // Preload: w1f[jb] is the A-fragment of W1T (scaled by S):
    //   lane supplies A[l15][8*lg+b] = S * W1[8*lg+b][16*jb+l15]
    // b1v[jb][r] = S * b1[16*jb+4*lg+r]   (C bias, matches D row layout)
    // n2w2[jb][r] = -2 * W2[16*jb+4*lg+r]; pbase = sum of this lane's w2 slice.
    bf16x8 w1f[4];
    f32x4  b1v[4];
    f32x4  n2w2[4];
    float  pbase = 0.f;
#pragma unroll
    for (int jb = 0; jb < 4; ++jb) {
        union { bf16x8 v; unsigned short u[8]; } t;
#pragma unroll
        for (int b = 0; b < 8; ++b)
            t.u[b] = f2bf(W1[(8 * lg + b) * 64 + 16 * jb + l15] * S);
        w1f[jb] = t.v;
#pragma unroll
        for (int r = 0; r < 4; ++r) {
            int h = 16 * jb + 4 * lg + r;
            b1v[jb][r] = b1[h] * S;
            float w = W2[h];
            n2w2[jb][r] = -2.0f * w;
            pbase += w;
        }
    }
    const float bias2 = b2[0];

    // B-fragment gather: lane supplies B[k=8*lg+b][edge l15] = concat feature k.
    // k 0..15 = bi = x[col] (edge_index[1]); k 16..31 = bo = x[row] (edge_index[0])
    const int which = (lane < 32) ? 1 : 0;
    const int feat8 = (lg & 1) * 8;

    auto load_node = [&](int t) -> int {
        int e  = t * 16 + l15;
        int ec = e < E ? e : E - 1;
        if (idx64) return ((const int*)ei)[2 * ((size_t)which * E + ec)];  // low word
        else       return ((const int*)ei)[(size_t)which * E + ec];
    };
    auto load_frag = [&](int node) -> bf16x8 {
        if (USE_XB) {
            return *(const bf16x8*)(xb + (size_t)node * 16 + feat8);
        } else {
            const float* px = x + (size_t)node * 16 + feat8;
            f32x4 v0 = *(const f32x4*)px;
            f32x4 v1 = *(const f32x4*)(px + 4);
            union { bf16x8 v; unsigned short u[8]; } t;
#pragma unroll
            for (int b = 0; b < 4; ++b) { t.u[b] = f2bf(v0[b]); t.u[b + 4] = f2bf(v1[b]); }
            return t.v;
        }
    };

    int tile = gwave;
    bf16x8 af = {};
    if (tile < ntiles) af = load_frag(load_node(tile));

    while (tile < ntiles) {
        bf16x8 a = af;
        int nt = tile + nwaves;
        if (nt < ntiles) af = load_frag(load_node(nt));   // prefetch next tile

        float p = pbase;
#pragma unroll
        for (int jb = 0; jb < 4; ++jb) {
            // D[4*lg+r][l15] = h_scaled[edge l15][hid 16*jb+4*lg+r]
            f32x4 acc = __builtin_amdgcn_mfma_f32_16x16x32_bf16(w1f[jb], a, b1v[jb], 0, 0, 0);
#pragma unroll
            for (int r = 0; r < 4; ++r) {
                float rv = RCPF(1.0f + EXP2F(acc[r]));   // (1+e^{2h})^-1
                p = fmaf(n2w2[jb][r], rv, p);            // p += w2 - 2*w2*rv (w2 in pbase)
            }
        }
        // reduce the 4 k-groups (lanes differing in bits 4,5)
        p += __shfl_xor(p, 16);
        p += __shfl_xor(p, 32);
        float sres = fast_sigmoid(p + bias2);
        int e0 = tile * 16 + l15;
        if (lane < 16 && e0 < E) out[e0] = sres;         // coalesced 16-lane store
        tile = nt;
    }
}

extern "C" void kernel_launch(void* const* d_in, const int* in_sizes, int n_in,
                              void* d_out, int out_size, void* d_ws, size_t ws_size,
                              hipStream_t stream)
{
    const float* x  = (const float*)d_in[0];
    const void*  ei = d_in[1];
    const float* W1 = (const float*)d_in[2];
    const float* b1 = (const float*)d_in[3];
    const float* W2 = (const float*)d_in[4];
    const float* b2 = (const float*)d_in[5];
    float* out = (float*)d_out;

    const int E      = in_sizes[1] / 2;
    const int nx     = in_sizes[0];
    const int ntiles = (E + 15) / 16;

    int* flag = nullptr;
    unsigned short* xb = nullptr;
    bool use_xb = false;
    if (ws_size >= 4) flag = (int*)d_ws;
    if (ws_size >= 256 + (size_t)nx * 2) {
        xb = (unsigned short*)((char*)d_ws + 256);
        use_xb = true;
    }

    if (flag) detect_idx64<<<1, 64, 0, stream>>>((const unsigned*)ei, flag);
    if (use_xb) {
        int nth = (nx + 3) / 4;
        cvt_x_bf16<<<(nth + 255) / 256, 256, 0, stream>>>(x, xb, nx);
    }

    const int blocks = 2048;
    if (use_xb)
        edge_mlp<true ><<<blocks, 256, 0, stream>>>(ei, x, xb, W1, b1, W2, b2, out, flag, E, ntiles);
    else
        edge_mlp<false><<<blocks, 256, 0, stream>>>(ei, x, xb, W1, b1, W2, b2, out, flag, E, ntiles);
}

// Round 3
// 69.958 us; speedup vs baseline: 1.4411x; 1.1163x over previous
//
#include <hip/hip_runtime.h>

// EdgeNetwork: out[e] = sigmoid( tanh( [x[col[e]], x[row[e]]] @ W1 + b1 ) @ W2 + b2 )
// E = 3.2M, IN=16, HID=64.
//
// R3: 32-edge tiles via mfma_f32_32x32x16_bf16 (swapped operands):
//   D[hid-in-block][edge] = W1T_blk @ Xconcat, 2 hid-blocks x 2 K-halves = 4 MFMA.
// Lane holds all 32 h of edge (lane&31) spread over rows (reg&3)+8*(reg>>2)+4*(lane>>5).
// Layer 2: per-lane pk_fma chain + 1 shfl_xor(32) + 1 sigmoid + coalesced store.
// tanh folded: W1,b1 pre-scaled by 2*log2e, tanh = 1 - 2*rcp(1+exp2(a));
// w2*tanh accumulated as pbase(=sum w2) + sum(-2*w2*rcp(...)).
// 2-deep pipeline: idx for t+2, gathers for t+1 in flight during compute of t.

typedef __attribute__((ext_vector_type(8)))  short bf16x8;
typedef __attribute__((ext_vector_type(2)))  float f32x2;
typedef __attribute__((ext_vector_type(4)))  float f32x4;
typedef __attribute__((ext_vector_type(16))) float f32x16;
typedef __attribute__((ext_vector_type(4)))  unsigned short u16x4;

#define LOG2E 1.4426950408889634f

#if defined(__has_builtin)
#if __has_builtin(__builtin_amdgcn_exp2f)
#define EXP2F __builtin_amdgcn_exp2f
#endif
#if __has_builtin(__builtin_amdgcn_rcpf)
#define RCPF __builtin_amdgcn_rcpf
#endif
#endif
#ifndef EXP2F
#define EXP2F exp2f
#endif
#ifndef RCPF
#define RCPF(x) (1.0f / (x))
#endif

template <bool B> struct BC { static constexpr bool value = B; };

__device__ __forceinline__ unsigned short f2bf(float f) {
    unsigned u = __float_as_uint(f);
    u += 0x7fffu + ((u >> 16) & 1u);
    return (unsigned short)(u >> 16);
}

// ---- x fp32 -> bf16, plus edge_index dtype detection (block 0, wave 0) ----
__global__ void prep(const float* __restrict__ x, unsigned short* __restrict__ xb, int n,
                     const unsigned* __restrict__ ei, int* __restrict__ flag) {
    if (blockIdx.x == 0 && threadIdx.x < 64) {
        unsigned v = ei[2 * threadIdx.x + 1];          // odd 32-bit words
        unsigned long long nz = __ballot(v != 0u);
        if (threadIdx.x == 0) flag[0] = (nz == 0ull) ? 1 : 0;
    }
    int i = (blockIdx.x * blockDim.x + threadIdx.x) * 4;
    if (i >= n) return;
    f32x4 v = *(const f32x4*)(x + i);
    u16x4 o;
    o[0] = f2bf(v[0]); o[1] = f2bf(v[1]); o[2] = f2bf(v[2]); o[3] = f2bf(v[3]);
    *(u16x4*)(xb + i) = o;
}

__global__ void detect_idx64(const unsigned* __restrict__ ei, int* __restrict__ flag) {
    unsigned v = ei[2 * threadIdx.x + 1];
    unsigned long long nz = __ballot(v != 0u);
    if (threadIdx.x == 0) flag[0] = (nz == 0ull) ? 1 : 0;
}

struct IdxPair { int c, r; };

template <bool USE_XB>
__global__ void __launch_bounds__(256)
edge_mlp(const void* __restrict__ ei,
         const float* __restrict__ x,
         const unsigned short* __restrict__ xb,
         const float* __restrict__ W1,
         const float* __restrict__ b1,
         const float* __restrict__ W2,
         const float* __restrict__ b2,
         float* __restrict__ out,
         const int* __restrict__ flag,
         int E, int ntiles)
{
    const int lane = threadIdx.x & 63;
    const int l31  = lane & 31;        // edge within tile (B col) / W1T row (hid)
    const int g    = lane >> 5;        // k-slot group (features 8g..8g+7)
    const int gwave  = blockIdx.x * (blockDim.x >> 6) + (threadIdx.x >> 6);
    const int nwaves = gridDim.x * (blockDim.x >> 6);

    const int idx64 = flag ? flag[0] : 0;
    const float S = 2.0f * LOG2E;

    // A-fragments of S*W1T: lane supplies A[row=l31][k-slot b] = S*W1[16*ks+8*g+b][32*blk+l31]
    bf16x8 w1f00, w1f01, w1f10, w1f11;
    {
        union { bf16x8 v; unsigned short u[8]; } t00, t01, t10, t11;
#pragma unroll
        for (int b = 0; b < 8; ++b) {
            int k0 = 8 * g + b;
            t00.u[b] = f2bf(S * W1[(k0)      * 64 + l31]);
            t01.u[b] = f2bf(S * W1[(16 + k0) * 64 + l31]);
            t10.u[b] = f2bf(S * W1[(k0)      * 64 + 32 + l31]);
            t11.u[b] = f2bf(S * W1[(16 + k0) * 64 + 32 + l31]);
        }
        w1f00 = t00.v; w1f01 = t01.v; w1f10 = t10.v; w1f11 = t11.v;
    }
    // C/D row layout (32x32): row = (reg&3) + 8*(reg>>2) + 4*g, col = l31
    f32x16 b1v0, b1v1;
    f32x2  w2a[8], w2b[8];
    float  pbase = 0.f;
#pragma unroll
    for (int reg = 0; reg < 16; ++reg) {
        int rowv = (reg & 3) + 8 * (reg >> 2) + 4 * g;
        b1v0[reg] = S * b1[rowv];
        b1v1[reg] = S * b1[32 + rowv];
        float wa = W2[rowv], wb = W2[32 + rowv];
        w2a[reg >> 1][reg & 1] = -2.0f * wa;
        w2b[reg >> 1][reg & 1] = -2.0f * wb;
        pbase += wa + wb;
    }
    const float bias2 = b2[0];

    auto body = [&](auto bc) {
        constexpr bool IDX64 = decltype(bc)::value;
        auto load_idx = [&](int tt) -> IdxPair {
            int e  = tt * 32 + l31;
            int ec = e < E ? e : E - 1;
            IdxPair ip;
            if (IDX64) {
                ip.r = ((const int*)ei)[2 * (size_t)ec];             // low word
                ip.c = ((const int*)ei)[2 * ((size_t)E + ec)];
            } else {
                ip.r = ((const int*)ei)[(size_t)ec];
                ip.c = ((const int*)ei)[(size_t)E + ec];
            }
            return ip;
        };
        auto gather = [&](int node) -> bf16x8 {
            if (USE_XB) {
                return *(const bf16x8*)(xb + (size_t)node * 16 + 8 * g);
            } else {
                const float* px = x + (size_t)node * 16 + 8 * g;
                f32x4 v0 = *(const f32x4*)px;
                f32x4 v1 = *(const f32x4*)(px + 4);
                union { bf16x8 v; unsigned short u[8]; } t;
#pragma unroll
                for (int b = 0; b < 4; ++b) { t.u[b] = f2bf(v0[b]); t.u[b + 4] = f2bf(v1[b]); }
                return t.v;
            }
        };

        int t = gwave;
        if (t >= ntiles) return;
        IdxPair ic = load_idx(t);
        bf16x8 fc = gather(ic.c);
        bf16x8 fr = gather(ic.r);
        int tn = t + nwaves;
        IdxPair inx = load_idx(tn < ntiles ? tn : ntiles - 1);

        while (true) {
            // prefetch: gathers for t+1, indices for t+2 (issue before compute)
            bf16x8 fcn = gather(inx.c);
            bf16x8 frn = gather(inx.r);
            int tnn = tn + nwaves;
            IdxPair inn = load_idx(tnn < ntiles ? tnn : ntiles - 1);

            // layer 1: 2 hid-blocks x 2 K-halves
            f32x16 acc0 = __builtin_amdgcn_mfma_f32_32x32x16_bf16(w1f00, fc, b1v0, 0, 0, 0);
            acc0        = __builtin_amdgcn_mfma_f32_32x32x16_bf16(w1f01, fr, acc0, 0, 0, 0);
            f32x16 acc1 = __builtin_amdgcn_mfma_f32_32x32x16_bf16(w1f10, fc, b1v1, 0, 0, 0);
            acc1        = __builtin_amdgcn_mfma_f32_32x32x16_bf16(w1f11, fr, acc1, 0, 0, 0);

            // layer 2: p = sum w2*tanh = pbase + sum(-2*w2 * rcp(1+exp2(acc)))
            f32x2 pv0 = { pbase, 0.0f };
            f32x2 pv1 = { 0.0f, 0.0f };
#pragma unroll
            for (int j = 0; j < 8; ++j) {
                f32x2 e0 = { EXP2F(acc0[2 * j]), EXP2F(acc0[2 * j + 1]) };
                f32x2 e1 = { EXP2F(acc1[2 * j]), EXP2F(acc1[2 * j + 1]) };
                f32x2 d0 = e0 + 1.0f;
                f32x2 d1 = e1 + 1.0f;
                f32x2 rv0 = { RCPF(d0[0]), RCPF(d0[1]) };
                f32x2 rv1 = { RCPF(d1[0]), RCPF(d1[1]) };
                pv0 += w2a[j] * rv0;          // v_pk_fma_f32 (hopefully)
                pv1 += w2b[j] * rv1;
            }
            float p = (pv0[0] + pv1[0]) + (pv0[1] + pv1[1]);
            p += __shfl_xor(p, 32);
            float z = p + bias2;
            float res = RCPF(1.0f + EXP2F(-z * LOG2E));
            int e0i = t * 32 + l31;
            if (lane < 32 && e0i < E) out[e0i] = res;   // coalesced 32-lane store

            if (tn >= ntiles) break;
            t = tn; tn = tnn;
            inx = inn; fc = fcn; fr = frn;
        }
    };

    if (idx64) body(BC<true>{});
    else       body(BC<false>{});
}

extern "C" void kernel_launch(void* const* d_in, const int* in_sizes, int n_in,
                              void* d_out, int out_size, void* d_ws, size_t ws_size,
                              hipStream_t stream)
{
    const float* x  = (const float*)d_in[0];
    const void*  ei = d_in[1];
    const float* W1 = (const float*)d_in[2];
    const float* b1 = (const float*)d_in[3];
    const float* W2 = (const float*)d_in[4];
    const float* b2 = (const float*)d_in[5];
    float* out = (float*)d_out;

    const int E      = in_sizes[1] / 2;
    const int nx     = in_sizes[0];
    const int ntiles = (E + 31) / 32;

    int* flag = nullptr;
    unsigned short* xb = nullptr;
    bool use_xb = false;
    if (ws_size >= 4) flag = (int*)d_ws;
    if (ws_size >= 256 + (size_t)nx * 2) {
        xb = (unsigned short*)((char*)d_ws + 256);
        use_xb = true;
    }

    if (use_xb) {
        int nth = (nx + 3) / 4;
        prep<<<(nth + 255) / 256, 256, 0, stream>>>(x, xb, nx, (const unsigned*)ei, flag);
    } else if (flag) {
        detect_idx64<<<1, 64, 0, stream>>>((const unsigned*)ei, flag);
    }

    const int blocks = 2048;
    if (use_xb)
        edge_mlp<true ><<<blocks, 256, 0, stream>>>(ei, x, xb, W1, b1, W2, b2, out, flag, E, ntiles);
    else
        edge_mlp<false><<<blocks, 256, 0, stream>>>(ei, x, xb, W1, b1, W2, b2, out, flag, E, ntiles);
}